// Round 1
// baseline (4816.298 us; speedup 1.0000x reference)
//
#include <hip/hip_runtime.h>
#include <hip/hip_bf16.h>
#include <math.h>

// ---------------------------------------------------------------------------
// Model: MoE-style expert mixing + 2 GCN layers.
// Key simplification: m depends only on argmax(logits) in {0,1,2}, so all
// m @ M products are 3-row lookup tables precomputed in k_prep0/k_prep1.
// result1 is never materialized: its GEMMs fold the c1[k] part into a
// precomputed 3x512 table (cwcat).
// ---------------------------------------------------------------------------

#define BM 128
#define BN 128
#define BK 16

__device__ __forceinline__ float4 ld4(const float* p) { return *(const float4*)p; }

// ---------------- prep: per-expert mixing vectors -------------------------
// a1v[k][j] = (m_k @ W1.sum(-1))[j]   (3x768)
// c1v[k][j] = (m_k @ bp1)[j]          (3x768)
// w12v[k][c]= (m_k @ W12)[c]          (3x256)
// a2v[k][c] = (m_k @ W2.sum(-1))[c]   (3x256)
// c2v[k][c] = (m_k @ bp2)[c]          (3x256)
__global__ __launch_bounds__(256) void k_prep0(
    const float* __restrict__ W1, const float* __restrict__ bp1,
    const float* __restrict__ W12, const float* __restrict__ W2,
    const float* __restrict__ bp2,
    float* __restrict__ a1v, float* __restrict__ c1v,
    float* __restrict__ w12v, float* __restrict__ a2v, float* __restrict__ c2v) {
  int j = blockIdx.x * 256 + threadIdx.x;
  if (j < 768) {
    float s[3];
    #pragma unroll
    for (int k = 0; k < 3; ++k) {
      const float* p = W1 + ((size_t)k * 768 + j) * 256;
      float t = 0.f;
      for (int l = 0; l < 256; ++l) t += p[l];
      s[k] = t;
    }
    float tot = s[0] + s[1] + s[2];
    #pragma unroll
    for (int k = 0; k < 3; ++k) a1v[k * 768 + j] = 0.15f * tot + 0.55f * s[k];
    float b0 = bp1[j], b1 = bp1[768 + j], b2 = bp1[1536 + j];
    float bt = b0 + b1 + b2;
    c1v[j]        = 0.15f * bt + 0.55f * b0;
    c1v[768 + j]  = 0.15f * bt + 0.55f * b1;
    c1v[1536 + j] = 0.15f * bt + 0.55f * b2;
  }
  if (j < 256) {
    // W12
    float w0 = W12[j], w1 = W12[256 + j], w2 = W12[512 + j];
    float wt = w0 + w1 + w2;
    w12v[j]       = 0.15f * wt + 0.55f * w0;
    w12v[256 + j] = 0.15f * wt + 0.55f * w1;
    w12v[512 + j] = 0.15f * wt + 0.55f * w2;
    // W2.sum(-1)
    float s[3];
    #pragma unroll
    for (int k = 0; k < 3; ++k) {
      const float* p = W2 + ((size_t)k * 256 + j) * 256;
      float t = 0.f;
      for (int l = 0; l < 256; ++l) t += p[l];
      s[k] = t;
    }
    float tot = s[0] + s[1] + s[2];
    #pragma unroll
    for (int k = 0; k < 3; ++k) a2v[k * 256 + j] = 0.15f * tot + 0.55f * s[k];
    float p0 = bp2[j], p1 = bp2[256 + j], p2 = bp2[512 + j];
    float pt = p0 + p1 + p2;
    c2v[j]       = 0.15f * pt + 0.55f * p0;
    c2v[256 + j] = 0.15f * pt + 0.55f * p1;
    c2v[512 + j] = 0.15f * pt + 0.55f * p2;
  }
}

// cwcat[k][0:256]  = c1[k] @ gcn1_w, cwcat[k][256:512] = c1[k] @ W13  (3x512)
// cw2[k][d]        = c2[k] @ gcn2_w                                    (3x32)
__global__ __launch_bounds__(256) void k_prep1(
    const float* __restrict__ c1v, const float* __restrict__ c2v,
    const float* __restrict__ gcn1w, const float* __restrict__ W13,
    const float* __restrict__ gcn2w,
    float* __restrict__ cwcat, float* __restrict__ cw2) {
  int gid = blockIdx.x * 256 + threadIdx.x;
  if (gid < 768) {
    int k = gid / 256, c = gid % 256;
    float s1 = 0.f, s2 = 0.f;
    for (int j = 0; j < 768; ++j) {
      float cv = c1v[k * 768 + j];
      s1 += cv * gcn1w[(size_t)j * 256 + c];
      s2 += cv * W13[(size_t)j * 256 + c];
    }
    cwcat[k * 512 + c] = s1;
    cwcat[k * 512 + 256 + c] = s2;
  } else if (gid < 768 + 96) {
    int t = gid - 768;
    int k = t / 32, d = t % 32;
    float s = 0.f;
    for (int j = 0; j < 256; ++j) s += c2v[k * 256 + j] * gcn2w[j * 32 + d];
    cw2[k * 32 + d] = s;
  }
}

// ---------------- degree / dinv -------------------------------------------
__global__ void k_count(const int* __restrict__ dst, float* deg, int E) {
  int e = blockIdx.x * 256 + threadIdx.x;
  if (e < E) atomicAdd(&deg[dst[e]], 1.0f);
}

__global__ void k_dinv(float* dinv, int N) {
  int i = blockIdx.x * 256 + threadIdx.x;
  if (i < N) {
    float d = dinv[i];
    dinv[i] = (d > 0.f) ? (1.0f / sqrtf(d)) : 0.f;
  }
}

// ---------------- tiled fp32 SGEMM: C = act(A@B + bias) -------------------
// A [M,Kk] row-major (lda=Kk), B [Kk,Nn] row-major (ldb), C (ldc).
__global__ __launch_bounds__(256) void k_sgemm(
    const float* __restrict__ A, const float* __restrict__ B,
    const float* __restrict__ bias, float* __restrict__ C,
    int M, int Kk, int ldb, int ldc, int do_relu) {
  __shared__ float As[BK][BM];
  __shared__ float Bs[BK][BN];
  int tid = threadIdx.x;
  int tx = tid & 15, ty = tid >> 4;
  int m0 = blockIdx.y * BM, n0 = blockIdx.x * BN;
  int ar = tid >> 2, ak = (tid & 3) << 2;   // A-tile load: row 0..63(+64), k 0..15
  int bk = tid >> 5, bn = (tid & 31) << 2;  // B-tile load: k 0..7(+8), n 0..127
  float acc[8][8] = {};
  for (int kt = 0; kt < Kk; kt += BK) {
    float4 aval[2], bval[2];
    #pragma unroll
    for (int r = 0; r < 2; ++r) {
      int row = m0 + ar + r * 64;
      aval[r] = (row < M) ? ld4(A + (size_t)row * Kk + kt + ak)
                          : float4{0.f, 0.f, 0.f, 0.f};
      bval[r] = ld4(B + (size_t)(kt + bk + r * 8) * ldb + n0 + bn);
    }
    __syncthreads();
    #pragma unroll
    for (int r = 0; r < 2; ++r) {
      int m = ar + r * 64;
      As[ak + 0][m] = aval[r].x;
      As[ak + 1][m] = aval[r].y;
      As[ak + 2][m] = aval[r].z;
      As[ak + 3][m] = aval[r].w;
      *(float4*)&Bs[bk + r * 8][bn] = bval[r];
    }
    __syncthreads();
    #pragma unroll
    for (int kk = 0; kk < BK; ++kk) {
      float av[8], bv[8];
      *(float4*)&av[0] = *(const float4*)&As[kk][ty * 8];
      *(float4*)&av[4] = *(const float4*)&As[kk][ty * 8 + 4];
      *(float4*)&bv[0] = *(const float4*)&Bs[kk][tx * 8];
      *(float4*)&bv[4] = *(const float4*)&Bs[kk][tx * 8 + 4];
      #pragma unroll
      for (int i = 0; i < 8; ++i)
        #pragma unroll
        for (int j = 0; j < 8; ++j)
          acc[i][j] = fmaf(av[i], bv[j], acc[i][j]);
    }
    __syncthreads();
  }
  float bia[8];
  *(float4*)&bia[0] = ld4(bias + n0 + tx * 8);
  *(float4*)&bia[4] = ld4(bias + n0 + tx * 8 + 4);
  #pragma unroll
  for (int i = 0; i < 8; ++i) {
    int row = m0 + ty * 8 + i;
    if (row < M) {
      float o[8];
      #pragma unroll
      for (int j = 0; j < 8; ++j) {
        float v = acc[i][j] + bia[j];
        o[j] = do_relu ? fmaxf(v, 0.f) : v;
      }
      float* cp = C + (size_t)row * ldc + n0 + tx * 8;
      *(float4*)cp = *(float4*)&o[0];
      *(float4*)(cp + 4) = *(float4*)&o[4];
    }
  }
}

// ---------------- mixed GEMM: h3t = (a1[k] . x2) @ [gcn1_w | W13] + cwcat[k]
// output [M,512]: cols 0..255 feed GCN1 aggregation, cols 256..511 = t13.
__global__ __launch_bounds__(256) void k_sgemm_mix(
    const float* __restrict__ X2, const float* __restrict__ a1v,
    const int* __restrict__ kidx,
    const float* __restrict__ B1, const float* __restrict__ B2,
    const float* __restrict__ cwcat, float* __restrict__ C, int M) {
  __shared__ float As[BK][BM];
  __shared__ float Bs[BK][BN];
  const int Kk = 768, ldc = 512;
  int tid = threadIdx.x;
  int tx = tid & 15, ty = tid >> 4;
  int m0 = blockIdx.y * BM, n0 = blockIdx.x * BN;
  const float* Bp = (n0 < 256) ? (B1 + n0) : (B2 + (n0 - 256));  // ldb=256
  int ar = tid >> 2, ak = (tid & 3) << 2;
  int bk = tid >> 5, bn = (tid & 31) << 2;
  float acc[8][8] = {};
  for (int kt = 0; kt < Kk; kt += BK) {
    float4 aval[2], bval[2];
    #pragma unroll
    for (int r = 0; r < 2; ++r) {
      int row = m0 + ar + r * 64;
      if (row < M) {
        int k = kidx[row];
        float4 x = ld4(X2 + (size_t)row * 768 + kt + ak);
        float4 s = ld4(a1v + k * 768 + kt + ak);
        aval[r] = float4{x.x * s.x, x.y * s.y, x.z * s.z, x.w * s.w};
      } else {
        aval[r] = float4{0.f, 0.f, 0.f, 0.f};
      }
      bval[r] = ld4(Bp + (size_t)(kt + bk + r * 8) * 256 + bn);
    }
    __syncthreads();
    #pragma unroll
    for (int r = 0; r < 2; ++r) {
      int m = ar + r * 64;
      As[ak + 0][m] = aval[r].x;
      As[ak + 1][m] = aval[r].y;
      As[ak + 2][m] = aval[r].z;
      As[ak + 3][m] = aval[r].w;
      *(float4*)&Bs[bk + r * 8][bn] = bval[r];
    }
    __syncthreads();
    #pragma unroll
    for (int kk = 0; kk < BK; ++kk) {
      float av[8], bv[8];
      *(float4*)&av[0] = *(const float4*)&As[kk][ty * 8];
      *(float4*)&av[4] = *(const float4*)&As[kk][ty * 8 + 4];
      *(float4*)&bv[0] = *(const float4*)&Bs[kk][tx * 8];
      *(float4*)&bv[4] = *(const float4*)&Bs[kk][tx * 8 + 4];
      #pragma unroll
      for (int i = 0; i < 8; ++i)
        #pragma unroll
        for (int j = 0; j < 8; ++j)
          acc[i][j] = fmaf(av[i], bv[j], acc[i][j]);
    }
    __syncthreads();
  }
  #pragma unroll
  for (int i = 0; i < 8; ++i) {
    int row = m0 + ty * 8 + i;
    if (row < M) {
      int k = kidx[row];
      const float* cv = cwcat + k * 512 + n0 + tx * 8;
      float o[8];
      #pragma unroll
      for (int j = 0; j < 8; ++j) o[j] = acc[i][j] + cv[j];
      float* cp = C + (size_t)row * ldc + n0 + tx * 8;
      *(float4*)cp = *(float4*)&o[0];
      *(float4*)(cp + 4) = *(float4*)&o[4];
    }
  }
}

// ---------------- router logits + argmax ----------------------------------
__global__ __launch_bounds__(256) void k_logits(
    const float* __restrict__ h2, const float* __restrict__ w3,
    const float* __restrict__ b3, int* __restrict__ kidx, int N) {
  __shared__ float sw[512 * 3];
  for (int t = threadIdx.x; t < 1536; t += 256) sw[t] = w3[t];
  __syncthreads();
  int wave = (blockIdx.x * 256 + threadIdx.x) >> 6;
  int lane = threadIdx.x & 63;
  int nw = gridDim.x * 4;
  for (int i = wave; i < N; i += nw) {
    const float* row = h2 + (size_t)i * 512 + lane * 8;
    float4 v0 = ld4(row), v1 = ld4(row + 4);
    float x[8] = {v0.x, v0.y, v0.z, v0.w, v1.x, v1.y, v1.z, v1.w};
    float p0 = 0.f, p1 = 0.f, p2 = 0.f;
    #pragma unroll
    for (int j = 0; j < 8; ++j) {
      int k = lane * 8 + j;
      p0 += x[j] * sw[k * 3 + 0];
      p1 += x[j] * sw[k * 3 + 1];
      p2 += x[j] * sw[k * 3 + 2];
    }
    #pragma unroll
    for (int off = 32; off >= 1; off >>= 1) {
      p0 += __shfl_xor(p0, off);
      p1 += __shfl_xor(p1, off);
      p2 += __shfl_xor(p2, off);
    }
    if (lane == 0) {
      p0 += b3[0]; p1 += b3[1]; p2 += b3[2];
      int best = 0; float bv = p0;
      if (p1 > bv) { bv = p1; best = 1; }
      if (p2 > bv) { bv = p2; best = 2; }
      kidx[i] = best;
    }
  }
}

// ---------------- GCN1 aggregation (256-dim, one wave per edge) -----------
__global__ __launch_bounds__(256) void k_agg1(
    const int* __restrict__ src, const int* __restrict__ dst,
    const float* __restrict__ dinv, const float* __restrict__ h3t,
    float* __restrict__ agg1, int E) {
  int wv = threadIdx.x >> 6, lane = threadIdx.x & 63;
  int e = blockIdx.x * 4 + wv;
  if (e >= E) return;
  int s = src[e], d = dst[e];
  float w = dinv[s] * dinv[d];
  float4 v = ld4(h3t + (size_t)s * 512 + lane * 4);
  float* base = agg1 + (size_t)d * 256 + lane * 4;
  atomicAdd(base + 0, v.x * w);
  atomicAdd(base + 1, v.y * w);
  atomicAdd(base + 2, v.z * w);
  atomicAdd(base + 3, v.w * w);
}

// ---------------- g1 / result2 / GEMM5 fused ------------------------------
// A'[i][j] = a2[k][j]*(w12[k][j]*relu(agg1[i][j]+gcn1_b[j]) + 2e-4*t13[i][j])
// h5[i]    = A'[i] @ gcn2_w + cw2[k]          (32 outputs per node)
__global__ __launch_bounds__(256) void k_g1r2(
    const float* __restrict__ agg1, const float* __restrict__ h3t,
    const float* __restrict__ gcn1_b, const float* __restrict__ w12v,
    const float* __restrict__ a2v, const float* __restrict__ gcn2w,
    const float* __restrict__ cw2, const int* __restrict__ kidx,
    float* __restrict__ h5, int N) {
  __shared__ float sW[256 * 32];
  __shared__ float sA[4][256];
  for (int t = threadIdx.x; t < 8192; t += 256) sW[t] = gcn2w[t];
  __syncthreads();
  int wv = threadIdx.x >> 6, lane = threadIdx.x & 63;
  int gw = blockIdx.x * 4 + wv, nw = gridDim.x * 4;
  for (int i = gw; i < N; i += nw) {
    int k = kidx[i];
    int j = lane * 4;
    float4 ag = ld4(agg1 + (size_t)i * 256 + j);
    float4 t13 = ld4(h3t + (size_t)i * 512 + 256 + j);
    float4 gb = ld4(gcn1_b + j);
    float4 wv4 = ld4(w12v + k * 256 + j);
    float4 a24 = ld4(a2v + k * 256 + j);
    float r[4];
    r[0] = a24.x * (wv4.x * fmaxf(ag.x + gb.x, 0.f) + 2e-4f * t13.x);
    r[1] = a24.y * (wv4.y * fmaxf(ag.y + gb.y, 0.f) + 2e-4f * t13.y);
    r[2] = a24.z * (wv4.z * fmaxf(ag.z + gb.z, 0.f) + 2e-4f * t13.z);
    r[3] = a24.w * (wv4.w * fmaxf(ag.w + gb.w, 0.f) + 2e-4f * t13.w);
    *(float4*)&sA[wv][j] = *(float4*)r;
    // per-wave LDS: intra-wave RAW handled by compiler lgkmcnt, no barrier
    int d = lane & 31, half = lane >> 5;
    float p = 0.f;
    const float* arow = sA[wv] + half * 128;
    const float* wp = sW + half * 128 * 32 + d;
    #pragma unroll 8
    for (int jj = 0; jj < 128; ++jj) p += arow[jj] * wp[jj * 32];
    p += __shfl_xor(p, 32);
    if (half == 0) h5[(size_t)i * 32 + d] = p + cw2[k * 32 + d];
  }
}

// ---------------- GCN2 aggregation (32-dim) -------------------------------
__global__ void k_agg2(
    const int* __restrict__ src, const int* __restrict__ dst,
    const float* __restrict__ dinv, const float* __restrict__ h5,
    float* __restrict__ agg2, int E) {
  int idx = blockIdx.x * 256 + threadIdx.x;
  if (idx >= E * 32) return;
  int e = idx >> 5, j = idx & 31;
  int s = src[e], d = dst[e];
  float w = dinv[s] * dinv[d];
  atomicAdd(&agg2[(size_t)d * 32 + j], h5[(size_t)s * 32 + j] * w);
}

// ---------------- final: relu + FC + log_softmax --------------------------
__global__ __launch_bounds__(256) void k_final(
    const float* __restrict__ agg2, const float* __restrict__ gcn2_b,
    const float* __restrict__ fc_w, const float* __restrict__ fc_b,
    float* __restrict__ out, int N) {
  __shared__ float sfw[32 * 40];
  __shared__ float sfb[40];
  __shared__ float sgb[32];
  for (int t = threadIdx.x; t < 1280; t += 256) sfw[t] = fc_w[t];
  if (threadIdx.x < 40) sfb[threadIdx.x] = fc_b[threadIdx.x];
  if (threadIdx.x < 32) sgb[threadIdx.x] = gcn2_b[threadIdx.x];
  __syncthreads();
  int i = blockIdx.x * 256 + threadIdx.x;
  if (i >= N) return;
  float g[32];
  #pragma unroll
  for (int jj = 0; jj < 32; jj += 4) {
    float4 v = ld4(agg2 + (size_t)i * 32 + jj);
    g[jj + 0] = fmaxf(v.x + sgb[jj + 0], 0.f);
    g[jj + 1] = fmaxf(v.y + sgb[jj + 1], 0.f);
    g[jj + 2] = fmaxf(v.z + sgb[jj + 2], 0.f);
    g[jj + 3] = fmaxf(v.w + sgb[jj + 3], 0.f);
  }
  float o[40];
  #pragma unroll
  for (int f = 0; f < 40; ++f) o[f] = sfb[f];
  #pragma unroll
  for (int j = 0; j < 32; ++j) {
    float gj = g[j];
    #pragma unroll
    for (int f = 0; f < 40; ++f) o[f] = fmaf(gj, sfw[j * 40 + f], o[f]);
  }
  float m = o[0];
  #pragma unroll
  for (int f = 1; f < 40; ++f) m = fmaxf(m, o[f]);
  float ssum = 0.f;
  #pragma unroll
  for (int f = 0; f < 40; ++f) ssum += expf(o[f] - m);
  float l = m + logf(ssum);
  float* op = out + (size_t)i * 40;
  #pragma unroll
  for (int f = 0; f < 40; f += 4) {
    float4 v = {o[f] - l, o[f + 1] - l, o[f + 2] - l, o[f + 3] - l};
    *(float4*)(op + f) = v;
  }
}

// ---------------------------------------------------------------------------
extern "C" void kernel_launch(void* const* d_in, const int* in_sizes, int n_in,
                              void* d_out, int out_size, void* d_ws, size_t ws_size,
                              hipStream_t stream) {
  const float* x1     = (const float*)d_in[0];
  const float* x2     = (const float*)d_in[1];
  const int*   ei     = (const int*)d_in[3];
  const float* mlp_w1 = (const float*)d_in[4];
  const float* mlp_b1 = (const float*)d_in[5];
  const float* mlp_w2 = (const float*)d_in[6];
  const float* mlp_b2 = (const float*)d_in[7];
  const float* mlp_w3 = (const float*)d_in[8];
  const float* mlp_b3 = (const float*)d_in[9];
  const float* W1     = (const float*)d_in[10];
  const float* W12    = (const float*)d_in[11];
  const float* W13    = (const float*)d_in[12];
  const float* bp1    = (const float*)d_in[13];
  const float* W2     = (const float*)d_in[14];
  const float* bp2    = (const float*)d_in[15];
  const float* gcn1_w = (const float*)d_in[16];
  const float* gcn1_b = (const float*)d_in[17];
  const float* gcn2_w = (const float*)d_in[18];
  const float* gcn2_b = (const float*)d_in[19];
  const float* fc_w   = (const float*)d_in[20];
  const float* fc_b   = (const float*)d_in[21];

  const int N = in_sizes[0] / 768;
  const int E = in_sizes[3] / 2;
  const int* e_src = ei;
  const int* e_dst = ei + E;

  // ---- workspace carve (floats) ----
  float* ws = (float*)d_ws;
  size_t off = 0;
  auto F = [&](size_t n) { float* p = ws + off; off += n; return p; };
  float* dinv  = F(N);             // deg then dinv
  int*   kidx  = (int*)F(N);
  float* a1v   = F(3 * 768);
  float* c1v   = F(3 * 768);
  float* w12v  = F(3 * 256);
  float* a2v   = F(3 * 256);
  float* c2v   = F(3 * 256);
  float* cwcat = F(3 * 512);
  float* cw2   = F(3 * 32);
  float* bufA  = F((size_t)N * 512);  // h1, then h3t (cols 0-255 h3, 256-511 t13)
  float* bufB  = F((size_t)N * 512);  // h2, then agg1 | h5 | agg2
  float* h1   = bufA;
  float* h2   = bufB;
  float* h3t  = bufA;
  float* agg1 = bufB;
  float* h5   = bufB + (size_t)N * 256;
  float* agg2 = bufB + (size_t)N * 288;

  // ---- prep ----
  k_prep0<<<3, 256, 0, stream>>>(W1, bp1, W12, W2, bp2, a1v, c1v, w12v, a2v, c2v);
  k_prep1<<<4, 256, 0, stream>>>(c1v, c2v, gcn1_w, W13, gcn2_w, cwcat, cw2);
  hipMemsetAsync(dinv, 0, (size_t)N * 4, stream);
  k_count<<<(E + 255) / 256, 256, 0, stream>>>(e_dst, dinv, E);
  k_dinv<<<(N + 255) / 256, 256, 0, stream>>>(dinv, N);

  // ---- MLP router ----
  dim3 gg(4, (N + BM - 1) / BM);
  k_sgemm<<<gg, 256, 0, stream>>>(x1, mlp_w1, mlp_b1, h1, N, 768, 512, 512, 1);
  k_sgemm<<<gg, 256, 0, stream>>>(h1, mlp_w2, mlp_b2, h2, N, 512, 512, 512, 1);
  k_logits<<<782, 256, 0, stream>>>(h2, mlp_w3, mlp_b3, kidx, N);

  // ---- result1 @ [gcn1_w | W13]  (result1 folded in) ----
  k_sgemm_mix<<<gg, 256, 0, stream>>>(x2, a1v, kidx, gcn1_w, W13, cwcat, h3t, N);

  // ---- GCN1 aggregation ----
  hipMemsetAsync(agg1, 0, (size_t)N * 256 * 4, stream);
  k_agg1<<<(E + 3) / 4, 256, 0, stream>>>(e_src, e_dst, dinv, h3t, agg1, E);

  // ---- g1, result2, GEMM with gcn2_w ----
  k_g1r2<<<4096, 256, 0, stream>>>(agg1, h3t, gcn1_b, w12v, a2v, gcn2_w, cw2,
                                   kidx, h5, N);

  // ---- GCN2 aggregation ----
  hipMemsetAsync(agg2, 0, (size_t)N * 32 * 4, stream);
  k_agg2<<<(E * 32 + 255) / 256, 256, 0, stream>>>(e_src, e_dst, dinv, h5, agg2, E);

  // ---- final FC + log_softmax ----
  k_final<<<(N + 255) / 256, 256, 0, stream>>>(agg2, gcn2_b, fc_w, fc_b,
                                               (float*)d_out, N);
}